// Round 1
// baseline (585.275 us; speedup 1.0000x reference)
//
#include <hip/hip_runtime.h>
#include <hip/hip_bf16.h>

typedef unsigned short u16;
typedef __attribute__((ext_vector_type(8))) short short8;
typedef __attribute__((ext_vector_type(4))) float floatx4;

#define B_SZ 2
#define M_SZ 2048
#define N_SZ 2048
#define SCALE_F 0.07216878364870323f  /* 1/sqrt(192) */

__device__ __forceinline__ u16 f2b(float f) {
    unsigned int x = __builtin_bit_cast(unsigned int, f);
    unsigned int r = (x + 0x7fffu + ((x >> 16) & 1u)) >> 16;   // RNE
    return (u16)r;
}
__device__ __forceinline__ float b2f(u16 u) {
    unsigned int x = ((unsigned int)u) << 16;
    return __builtin_bit_cast(float, x);
}
__device__ __forceinline__ void async16(const void* g, void* l) {
    __builtin_amdgcn_global_load_lds(
        (const __attribute__((address_space(1))) void*)g,
        (__attribute__((address_space(3))) void*)l, 16, 0, 0);
}

// ---------------------------------------------------------------- casts
__global__ void cast_k(const float* __restrict__ s, u16* __restrict__ d, long n)
{
    const long i = ((long)blockIdx.x * 256 + threadIdx.x) * 4;
    if (i >= n) return;
    const float4 v = *(const float4*)(s + i);
    unsigned long long pk = (unsigned long long)f2b(v.x)
                          | ((unsigned long long)f2b(v.y) << 16)
                          | ((unsigned long long)f2b(v.z) << 32)
                          | ((unsigned long long)f2b(v.w) << 48);
    *(unsigned long long*)(d + i) = pk;
}

// ---------------------------------------------------------------- RoPE (in place, bf16)
// buf: 4096 rows x 1024 cols (16 heads x 64). Interleaved-pair rotation.
__global__ void rope_k(u16* __restrict__ buf)
{
    const int idx = blockIdx.x * 256 + threadIdx.x;   // 0..2097151
    const int row = idx >> 9;                          // 0..4095
    const int pr  = idx & 511;                         // pair within row
    const int j   = pr & 31;                           // pair within head
    const int pos = row & 2047;
    const float f   = powf(1.0e6f, -(float)j * (1.0f / 32.0f));
    const float ang = (float)pos * f;
    float sn, cs;
    sincosf(ang, &sn, &cs);
    u16* pp = buf + ((long)row << 10) + (pr << 1);
    const float x0 = b2f(pp[0]);
    const float x1 = b2f(pp[1]);
    pp[0] = f2b(x0 * cs - x1 * sn);
    pp[1] = f2b(x1 * cs + x0 * sn);
}

// ---------------------------------------------------------------- GEMM  C = A(MxK) * B(NxK)^T
// MODE 0: bf16 out row-major (ld=Ndim). MODE 1: bf16 out transposed V layout (b,h,d,n).
// MODE 2: f32 out row-major.
template<int MODE>
__global__ void __launch_bounds__(256, 2)
gemm_bt(const u16* __restrict__ A, const u16* __restrict__ Bw,
        void* __restrict__ Cout, int K, int Ndim)
{
    __shared__ u16 As[128 * 64];
    __shared__ u16 Bs[128 * 64];
    const int t = threadIdx.x;
    const int w = t >> 6;
    const int lane = t & 63;
    const int lq = lane >> 4, lr = lane & 15;
    const long tileM = (long)blockIdx.x * 128;
    const long tileN = (long)blockIdx.y * 128;
    const int wm = (w >> 1) * 64, wn = (w & 1) * 64;

    const floatx4 fzero = {0.f, 0.f, 0.f, 0.f};
    floatx4 acc[4][4];
#pragma unroll
    for (int i = 0; i < 4; ++i)
#pragma unroll
        for (int j = 0; j < 4; ++j) acc[i][j] = fzero;

    for (int k0 = 0; k0 < K; k0 += 64) {
#pragma unroll
        for (int r = 0; r < 4; ++r) {
            const int c = r * 256 + t;              // 0..1023
            const int row = c >> 3, cc = c & 7;
            const int gcol = ((cc ^ (row & 7)) << 3);
            async16(A + (tileM + row) * (long)K + k0 + gcol, (char*)As + c * 16);
        }
#pragma unroll
        for (int r = 0; r < 4; ++r) {
            const int c = r * 256 + t;
            const int row = c >> 3, cc = c & 7;
            const int gcol = ((cc ^ (row & 7)) << 3);
            async16(Bw + (tileN + row) * (long)K + k0 + gcol, (char*)Bs + c * 16);
        }
        __builtin_amdgcn_s_waitcnt(0);
        __syncthreads();
#pragma unroll
        for (int kk = 0; kk < 2; ++kk) {
            short8 af[4], bfr[4];
#pragma unroll
            for (int i = 0; i < 4; ++i) {
                const int row = wm + 16 * i + lr;
                const int cc = (kk * 4 + lq) ^ (row & 7);
                af[i] = *(const short8*)(As + row * 64 + cc * 8);
            }
#pragma unroll
            for (int j = 0; j < 4; ++j) {
                const int row = wn + 16 * j + lr;
                const int cc = (kk * 4 + lq) ^ (row & 7);
                bfr[j] = *(const short8*)(Bs + row * 64 + cc * 8);
            }
#pragma unroll
            for (int i = 0; i < 4; ++i)
#pragma unroll
                for (int j = 0; j < 4; ++j)
                    acc[i][j] = __builtin_amdgcn_mfma_f32_16x16x32_bf16(
                        af[i], bfr[j], acc[i][j], 0, 0, 0);
        }
        __syncthreads();
    }

#pragma unroll
    for (int i = 0; i < 4; ++i) {
#pragma unroll
        for (int j = 0; j < 4; ++j) {
            const long row0 = tileM + wm + 16 * i + 4 * lq;
            const long col  = tileN + wn + 16 * j + lr;
#pragma unroll
            for (int r = 0; r < 4; ++r) {
                const float v = acc[i][j][r];
                const long row = row0 + r;
                if (MODE == 0) {
                    ((u16*)Cout)[row * Ndim + col] = f2b(v);
                } else if (MODE == 1) {
                    // V transposed: (b, hd, n)  with n-size 2048
                    const long b = row >> 11, nn = row & 2047;
                    ((u16*)Cout)[((b * 2048 + col) << 11) + nn] = f2b(v);
                } else {
                    ((float*)Cout)[row * Ndim + col] = v;
                }
            }
        }
    }
}

// ---------------------------------------------------------------- flash attention
// grid (M/128, H, B), 256 threads (4 waves), wave owns a 32-row Q strip.
__global__ void __launch_bounds__(256, 2)
flash_attn(const u16* __restrict__ QC, const u16* __restrict__ QR,
           const u16* __restrict__ KC, const u16* __restrict__ KR,
           const u16* __restrict__ VT, u16* __restrict__ Obuf)
{
    __shared__ u16 KC_s[64 * 128];
    __shared__ u16 KR_s[64 * 64];
    __shared__ u16 VT_s[128 * 64];
    __shared__ u16 P_s[4][32 * 72];   // per-wave P strip, padded stride 72

    const int t = threadIdx.x;
    const int w = t >> 6;
    const int lane = t & 63;
    const int lq = lane >> 4, lr = lane & 15;
    const int mb = blockIdx.x;
    const int h  = blockIdx.y;
    const int b  = blockIdx.z;
    const int mbase = mb * 128 + w * 32;

    // Q fragments (A-layout) held in registers: 6 K-chunks of 32 (4 from QC, 2 from QR)
    short8 aq[2][6];
#pragma unroll
    for (int i = 0; i < 2; ++i) {
        const long m = mbase + 16 * i + lr;
        const u16* qc = QC + ((long)b * M_SZ + m) * 2048 + h * 128;
        const u16* qr = QR + ((long)b * M_SZ + m) * 1024 + h * 64;
#pragma unroll
        for (int kc = 0; kc < 4; ++kc) aq[i][kc]     = *(const short8*)(qc + kc * 32 + lq * 8);
#pragma unroll
        for (int kc = 0; kc < 2; ++kc) aq[i][4 + kc] = *(const short8*)(qr + kc * 32 + lq * 8);
    }

    const floatx4 fzero = {0.f, 0.f, 0.f, 0.f};
    float mst[2][4], lst[2][4];
    floatx4 oacc[2][8];
#pragma unroll
    for (int i = 0; i < 2; ++i) {
#pragma unroll
        for (int r = 0; r < 4; ++r) { mst[i][r] = -1e30f; lst[i][r] = 0.f; }
#pragma unroll
        for (int jn = 0; jn < 8; ++jn) oacc[i][jn] = fzero;
    }

    const u16* kc_g = KC + ((long)b * N_SZ) * 2048 + h * 128;
    const u16* kr_g = KR + ((long)b * N_SZ) * 1024 + h * 64;
    const u16* vt_g = VT + ((long)(b * 16 + h) * 128) * 2048;

    for (int kt = 0; kt < 32; ++kt) {
        // ---- stage K_C (64x128), K_R (64x64), V^T (128x64)
#pragma unroll
        for (int r = 0; r < 4; ++r) {
            const int c = r * 256 + t;
            const int krow = c >> 4, cc = c & 15;
            const int gc = cc ^ (krow & 7);
            async16(kc_g + (long)(kt * 64 + krow) * 2048 + gc * 8, (char*)KC_s + c * 16);
        }
#pragma unroll
        for (int r = 0; r < 2; ++r) {
            const int c = r * 256 + t;
            const int krow = c >> 3, cc = c & 7;
            const int gc = cc ^ (krow & 7);
            async16(kr_g + (long)(kt * 64 + krow) * 1024 + gc * 8, (char*)KR_s + c * 16);
        }
#pragma unroll
        for (int r = 0; r < 4; ++r) {
            const int c = r * 256 + t;
            const int drow = c >> 3, cc = c & 7;
            const int gc = cc ^ (drow & 7);
            async16(vt_g + (long)drow * 2048 + kt * 64 + gc * 8, (char*)VT_s + c * 16);
        }
        __builtin_amdgcn_s_waitcnt(0);
        __syncthreads();

        // ---- S = Q K^T  (K-dim 192 = 6 chunks of 32)
        floatx4 s[2][4];
#pragma unroll
        for (int i = 0; i < 2; ++i)
#pragma unroll
            for (int j = 0; j < 4; ++j) s[i][j] = fzero;
#pragma unroll
        for (int kc = 0; kc < 6; ++kc) {
            short8 bfr[4];
#pragma unroll
            for (int j = 0; j < 4; ++j) {
                const int krow = 16 * j + lr;
                if (kc < 4) {
                    const int cc = (4 * kc + lq) ^ (krow & 7);
                    bfr[j] = *(const short8*)(KC_s + krow * 128 + cc * 8);
                } else {
                    const int cc = (4 * (kc - 4) + lq) ^ (krow & 7);
                    bfr[j] = *(const short8*)(KR_s + krow * 64 + cc * 8);
                }
            }
#pragma unroll
            for (int i = 0; i < 2; ++i)
#pragma unroll
                for (int j = 0; j < 4; ++j)
                    s[i][j] = __builtin_amdgcn_mfma_f32_16x16x32_bf16(
                        aq[i][kc], bfr[j], s[i][j], 0, 0, 0);
        }

        // ---- online softmax (per row: row = 16i + 4*lq + r within strip)
#pragma unroll
        for (int i = 0; i < 2; ++i) {
            float rmax[4], rsum[4], alpha[4];
#pragma unroll
            for (int j = 0; j < 4; ++j)
#pragma unroll
                for (int r = 0; r < 4; ++r) s[i][j][r] *= SCALE_F;
#pragma unroll
            for (int r = 0; r < 4; ++r)
                rmax[r] = fmaxf(fmaxf(s[i][0][r], s[i][1][r]), fmaxf(s[i][2][r], s[i][3][r]));
#pragma unroll
            for (int d = 1; d < 16; d <<= 1)
#pragma unroll
                for (int r = 0; r < 4; ++r)
                    rmax[r] = fmaxf(rmax[r], __shfl_xor(rmax[r], d, 64));
#pragma unroll
            for (int r = 0; r < 4; ++r) {
                const float mnew = fmaxf(mst[i][r], rmax[r]);
                alpha[r] = __expf(mst[i][r] - mnew);
                mst[i][r] = mnew;
                rsum[r] = 0.f;
            }
#pragma unroll
            for (int j = 0; j < 4; ++j)
#pragma unroll
                for (int r = 0; r < 4; ++r) {
                    const float p = __expf(s[i][j][r] - mst[i][r]);
                    s[i][j][r] = p;
                    rsum[r] += p;
                }
#pragma unroll
            for (int d = 1; d < 16; d <<= 1)
#pragma unroll
                for (int r = 0; r < 4; ++r)
                    rsum[r] += __shfl_xor(rsum[r], d, 64);
#pragma unroll
            for (int r = 0; r < 4; ++r)
                lst[i][r] = lst[i][r] * alpha[r] + rsum[r];
#pragma unroll
            for (int jn = 0; jn < 8; ++jn)
#pragma unroll
                for (int r = 0; r < 4; ++r) oacc[i][jn][r] *= alpha[r];
            // write P strip (C-layout -> LDS, padded)
            u16* pw = &P_s[w][0];
#pragma unroll
            for (int j = 0; j < 4; ++j)
#pragma unroll
                for (int r = 0; r < 4; ++r)
                    pw[(16 * i + 4 * lq + r) * 72 + 16 * j + lr] = f2b(s[i][j][r]);
        }

        // ---- O += P V   (A from P_s, B from VT_s)
#pragma unroll
        for (int kc = 0; kc < 2; ++kc) {
            short8 ap[2];
#pragma unroll
            for (int i = 0; i < 2; ++i)
                ap[i] = *(const short8*)(&P_s[w][0] + (16 * i + lr) * 72 + kc * 32 + lq * 8);
#pragma unroll
            for (int jn = 0; jn < 8; ++jn) {
                const int drow = 16 * jn + lr;
                const int cc = (4 * kc + lq) ^ (drow & 7);
                const short8 bv = *(const short8*)(VT_s + drow * 64 + cc * 8);
#pragma unroll
                for (int i = 0; i < 2; ++i)
                    oacc[i][jn] = __builtin_amdgcn_mfma_f32_16x16x32_bf16(
                        ap[i], bv, oacc[i][jn], 0, 0, 0);
            }
        }
        __syncthreads();
    }

    // ---- epilogue: O / l -> bf16
#pragma unroll
    for (int i = 0; i < 2; ++i)
#pragma unroll
        for (int jn = 0; jn < 8; ++jn)
#pragma unroll
            for (int r = 0; r < 4; ++r) {
                const long row = mbase + 16 * i + 4 * lq + r;
                const int d = 16 * jn + lr;
                const float v = oacc[i][jn][r] / lst[i][r];
                Obuf[((long)b * M_SZ + row) * 2048 + h * 128 + d] = f2b(v);
            }
}

// ---------------------------------------------------------------- launch
extern "C" void kernel_launch(void* const* d_in, const int* in_sizes, int n_in,
                              void* d_out, int out_size, void* d_ws, size_t ws_size,
                              hipStream_t stream)
{
    (void)in_sizes; (void)n_in; (void)out_size; (void)ws_size;
    const float* q   = (const float*)d_in[0];
    const float* kv  = (const float*)d_in[1];
    const float* wqc = (const float*)d_in[2];
    const float* wkc = (const float*)d_in[3];
    const float* wqr = (const float*)d_in[4];
    const float* wkr = (const float*)d_in[5];
    const float* wv  = (const float*)d_in[6];
    const float* wo  = (const float*)d_in[7];

    u16* p = (u16*)d_ws;
    u16* qbf  = p; p += 8388608;
    u16* kvbf = p; p += 8388608;
    u16* wqcb = p; p += 4194304;
    u16* wkcb = p; p += 4194304;
    u16* wqrb = p; p += 2097152;
    u16* wkrb = p; p += 2097152;
    u16* wvb  = p; p += 4194304;
    u16* wob  = p; p += 4194304;
    u16* QCb  = p; p += 8388608;
    u16* KCb  = p; p += 8388608;
    u16* QRb  = p; p += 4194304;
    u16* KRb  = p; p += 4194304;
    u16* VTb  = p; p += 8388608;
    u16* Ob   = p; p += 8388608;
    // total 159.4 MB of d_ws

    cast_k<<<8192, 256, 0, stream>>>(q,   qbf,  8388608);
    cast_k<<<8192, 256, 0, stream>>>(kv,  kvbf, 8388608);
    cast_k<<<4096, 256, 0, stream>>>(wqc, wqcb, 4194304);
    cast_k<<<4096, 256, 0, stream>>>(wkc, wkcb, 4194304);
    cast_k<<<2048, 256, 0, stream>>>(wqr, wqrb, 2097152);
    cast_k<<<2048, 256, 0, stream>>>(wkr, wkrb, 2097152);
    cast_k<<<4096, 256, 0, stream>>>(wv,  wvb,  4194304);
    cast_k<<<4096, 256, 0, stream>>>(wo,  wob,  4194304);

    dim3 g1(32, 16), g2(32, 8);
    gemm_bt<0><<<g1, 256, 0, stream>>>(qbf,  wqcb, QCb, 2048, 2048);
    gemm_bt<0><<<g1, 256, 0, stream>>>(kvbf, wkcb, KCb, 2048, 2048);
    gemm_bt<0><<<g2, 256, 0, stream>>>(qbf,  wqrb, QRb, 2048, 1024);
    gemm_bt<0><<<g2, 256, 0, stream>>>(kvbf, wkrb, KRb, 2048, 1024);
    gemm_bt<1><<<g1, 256, 0, stream>>>(kvbf, wvb,  VTb, 2048, 2048);

    rope_k<<<8192, 256, 0, stream>>>(QRb);
    rope_k<<<8192, 256, 0, stream>>>(KRb);

    dim3 gf(16, 16, 2);
    flash_attn<<<gf, 256, 0, stream>>>(QCb, QRb, KCb, KRb, VTb, Ob);

    gemm_bt<2><<<g1, 256, 0, stream>>>(Ob, wob, d_out, 2048, 2048);
}

// Round 3
// 513.871 us; speedup vs baseline: 1.1390x; 1.1390x over previous
//
#include <hip/hip_runtime.h>
#include <hip/hip_bf16.h>

typedef unsigned short u16;
typedef unsigned int u32;
typedef unsigned long long u64;
typedef __attribute__((ext_vector_type(8))) short short8;
typedef __attribute__((ext_vector_type(4))) float floatx4;

#if __has_builtin(__builtin_amdgcn_exp2f)
#define EXP2F(x) __builtin_amdgcn_exp2f(x)
#else
#define EXP2F(x) exp2f(x)
#endif

// SCALE * log2(e): softmax runs in base 2, scale pre-folded into Q cast.
#define QSCALE (0.07216878364870323f * 1.4426950408889634f)
#define ROPE_C 0.62286151779f   /* log2(1e6)/32 */

__device__ __forceinline__ u16 f2b(float f) {
    unsigned int x = __builtin_bit_cast(unsigned int, f);
    unsigned int r = (x + 0x7fffu + ((x >> 16) & 1u)) >> 16;   // RNE
    return (u16)r;
}
__device__ __forceinline__ u32 pk2(float a, float b) {
    return (u32)f2b(a) | ((u32)f2b(b) << 16);   // low 16 = a, high 16 = b
}
__device__ __forceinline__ void async16(const void* g, void* l) {
    __builtin_amdgcn_global_load_lds(
        (const __attribute__((address_space(1))) void*)g,
        (__attribute__((address_space(3))) void*)l, 16, 0, 0);
}

// ---------------------------------------------------------------- fused cast
struct CastArgs {
    const float* src[8];
    u16* dst[8];
    float scale[8];
    int startblk[8];
};

__global__ void cast_all_k(CastArgs a)
{
    const int bid = blockIdx.x;
    int s = 0;
#pragma unroll
    for (int i = 1; i < 8; ++i) s += (bid >= a.startblk[i]);
    const long idx = ((long)(bid - a.startblk[s]) * 256 + threadIdx.x) * 4;
    const float4 v = *(const float4*)(a.src[s] + idx);
    const float sc = a.scale[s];
    const u64 pk = (u64)pk2(v.x * sc, v.y * sc)
                 | ((u64)pk2(v.z * sc, v.w * sc) << 32);
    *(u64*)(a.dst[s] + idx) = pk;
}

// ---------------------------------------------------------------- GEMM  C = A(MxK) * B(NxK)^T
// EPI 0 (Q merged, N=3072): col<2048 -> QC bf16 (ld 2048); col>=2048 -> RoPE -> QR (ld 1024)
// EPI 1 (KV merged, N=5120): col<2048 -> KC; 2048..3071 -> RoPE -> KR; >=3072 -> V transposed (b,hd,n)
// EPI 2 (final, N=2048): f32 row-major
template<int EPI>
__global__ void __launch_bounds__(256, 3)
gemm_bt(const u16* __restrict__ A, const u16* __restrict__ Bw,
        void* __restrict__ out0, u16* __restrict__ out1, u16* __restrict__ out2,
        int K)
{
    __shared__ u16 As[128 * 64];
    __shared__ u16 Bs[128 * 64];
    const int t = threadIdx.x;
    const int w = t >> 6;
    const int lane = t & 63;
    const int lq = lane >> 4, lr = lane & 15;
    const long tileM = (long)blockIdx.x * 128;
    const long tileN = (long)blockIdx.y * 128;
    const int wm = (w >> 1) * 64, wn = (w & 1) * 64;

    const floatx4 fzero = {0.f, 0.f, 0.f, 0.f};
    floatx4 acc[4][4];
#pragma unroll
    for (int i = 0; i < 4; ++i)
#pragma unroll
        for (int j = 0; j < 4; ++j) acc[i][j] = fzero;

    for (int k0 = 0; k0 < K; k0 += 64) {
#pragma unroll
        for (int r = 0; r < 4; ++r) {
            const int c = r * 256 + t;
            const int row = c >> 3, cc = c & 7;
            const int gcol = ((cc ^ (row & 7)) << 3);
            async16(A + (tileM + row) * (long)K + k0 + gcol, (char*)As + c * 16);
        }
#pragma unroll
        for (int r = 0; r < 4; ++r) {
            const int c = r * 256 + t;
            const int row = c >> 3, cc = c & 7;
            const int gcol = ((cc ^ (row & 7)) << 3);
            async16(Bw + (tileN + row) * (long)K + k0 + gcol, (char*)Bs + c * 16);
        }
        __builtin_amdgcn_s_waitcnt(0);
        __syncthreads();
#pragma unroll
        for (int kk = 0; kk < 2; ++kk) {
            short8 af[4], bfr[4];
#pragma unroll
            for (int i = 0; i < 4; ++i) {
                const int row = wm + 16 * i + lr;
                const int cc = (kk * 4 + lq) ^ (row & 7);
                af[i] = *(const short8*)(As + row * 64 + cc * 8);
            }
#pragma unroll
            for (int j = 0; j < 4; ++j) {
                const int row = wn + 16 * j + lr;
                const int cc = (kk * 4 + lq) ^ (row & 7);
                bfr[j] = *(const short8*)(Bs + row * 64 + cc * 8);
            }
#pragma unroll
            for (int i = 0; i < 4; ++i)
#pragma unroll
                for (int j = 0; j < 4; ++j)
                    acc[i][j] = __builtin_amdgcn_mfma_f32_16x16x32_bf16(
                        af[i], bfr[j], acc[i][j], 0, 0, 0);
        }
        __syncthreads();
    }

    // ---- epilogue (region is block-uniform: boundaries are multiples of 128)
    const bool isV    = (EPI == 1) && (tileN >= 3072);
    const bool isRope = (EPI != 2) && !isV && (tileN >= 2048);

#pragma unroll
    for (int i = 0; i < 4; ++i) {
#pragma unroll
        for (int j = 0; j < 4; ++j) {
            const long row0 = tileM + wm + 16 * i + 4 * lq;
            const long col  = tileN + wn + 16 * j + lr;
            if (EPI == 2) {
#pragma unroll
                for (int r = 0; r < 4; ++r)
                    ((float*)out0)[(row0 + r) * 2048 + col] = acc[i][j][r];
            } else if (isV) {
                const u32 lo = pk2(acc[i][j][0], acc[i][j][1]);
                const u32 hi = pk2(acc[i][j][2], acc[i][j][3]);
                const long bb = row0 >> 11;
                u16* dst = out2 + ((bb * 2048 + (col - 3072)) << 11) + (row0 & 2047);
                *(uint2*)dst = make_uint2(lo, hi);
            } else if (isRope) {
                const int jj = ((int)col & 63) >> 1;
                const float freq = EXP2F(-ROPE_C * (float)jj);
#pragma unroll
                for (int r = 0; r < 4; ++r) {
                    const float v = acc[i][j][r];
                    const float vp = __shfl_xor(v, 1, 64);
                    const long row = row0 + r;
                    float sn, cs;
                    __sincosf((float)(row & 2047) * freq, &sn, &cs);
                    const float o = (col & 1) ? (v * cs + vp * sn) : (v * cs - vp * sn);
                    out1[row * 1024 + (col - 2048)] = f2b(o);
                }
            } else {
#pragma unroll
                for (int r = 0; r < 4; ++r)
                    ((u16*)out0)[(row0 + r) * 2048 + col] = f2b(acc[i][j][r]);
            }
        }
    }
}

// ---------------------------------------------------------------- flash attention
// grid (M/128, H, B), 256 threads (4 waves), wave owns a 32-row Q strip.
// Q pre-scaled by SCALE*log2e -> softmax in base 2 (exp2 = native v_exp_f32).
__global__ void __launch_bounds__(256, 2)
flash_attn(const u16* __restrict__ QC, const u16* __restrict__ QR,
           const u16* __restrict__ KC, const u16* __restrict__ KR,
           const u16* __restrict__ VT, u16* __restrict__ Obuf)
{
    __shared__ u16 KC_s[64 * 128];
    __shared__ u16 KR_s[64 * 64];
    __shared__ u16 VT_s[128 * 64];
    __shared__ u16 P_s[4][32 * 72];

    const int t = threadIdx.x;
    const int w = t >> 6;
    const int lane = t & 63;
    const int lq = lane >> 4, lr = lane & 15;
    const int mbase = blockIdx.x * 128 + w * 32;
    const int h = blockIdx.y, b = blockIdx.z;

    short8 aq[2][6];
#pragma unroll
    for (int i = 0; i < 2; ++i) {
        const long m = mbase + 16 * i + lr;
        const u16* qc = QC + ((long)b * 2048 + m) * 2048 + h * 128;
        const u16* qr = QR + ((long)b * 2048 + m) * 1024 + h * 64;
#pragma unroll
        for (int kc = 0; kc < 4; ++kc) aq[i][kc]     = *(const short8*)(qc + kc * 32 + lq * 8);
#pragma unroll
        for (int kc = 0; kc < 2; ++kc) aq[i][4 + kc] = *(const short8*)(qr + kc * 32 + lq * 8);
    }

    const floatx4 fzero = {0.f, 0.f, 0.f, 0.f};
    float mst[2][4], lst[2][4];
    floatx4 oacc[2][8];
#pragma unroll
    for (int i = 0; i < 2; ++i) {
#pragma unroll
        for (int r = 0; r < 4; ++r) { mst[i][r] = -1e30f; lst[i][r] = 0.f; }
#pragma unroll
        for (int jn = 0; jn < 8; ++jn) oacc[i][jn] = fzero;
    }

    const u16* kc_g = KC + ((long)b * 2048) * 2048 + h * 128;
    const u16* kr_g = KR + ((long)b * 2048) * 1024 + h * 64;
    const u16* vt_g = VT + ((long)(b * 16 + h) * 128) * 2048;

    for (int kt = 0; kt < 32; ++kt) {
#pragma unroll
        for (int r = 0; r < 4; ++r) {
            const int c = r * 256 + t;
            const int krow = c >> 4, cc = c & 15;
            const int gc = cc ^ (krow & 7);
            async16(kc_g + (long)(kt * 64 + krow) * 2048 + gc * 8, (char*)KC_s + c * 16);
        }
#pragma unroll
        for (int r = 0; r < 2; ++r) {
            const int c = r * 256 + t;
            const int krow = c >> 3, cc = c & 7;
            const int gc = cc ^ (krow & 7);
            async16(kr_g + (long)(kt * 64 + krow) * 1024 + gc * 8, (char*)KR_s + c * 16);
        }
#pragma unroll
        for (int r = 0; r < 4; ++r) {
            const int c = r * 256 + t;
            const int drow = c >> 3, cc = c & 7;
            const int gc = cc ^ (drow & 7);
            async16(vt_g + (long)drow * 2048 + kt * 64 + gc * 8, (char*)VT_s + c * 16);
        }
        __builtin_amdgcn_s_waitcnt(0);
        __syncthreads();

        // ---- S = Q K^T (K-dim 192 = 6 chunks of 32)
        floatx4 s[2][4];
#pragma unroll
        for (int i = 0; i < 2; ++i)
#pragma unroll
            for (int j = 0; j < 4; ++j) s[i][j] = fzero;
#pragma unroll
        for (int kc = 0; kc < 6; ++kc) {
            short8 bfr[4];
#pragma unroll
            for (int j = 0; j < 4; ++j) {
                const int krow = 16 * j + lr;
                if (kc < 4) {
                    const int cc = (4 * kc + lq) ^ (krow & 7);
                    bfr[j] = *(const short8*)(KC_s + krow * 128 + cc * 8);
                } else {
                    const int cc = (4 * (kc - 4) + lq) ^ (krow & 7);
                    bfr[j] = *(const short8*)(KR_s + krow * 64 + cc * 8);
                }
            }
#pragma unroll
            for (int i = 0; i < 2; ++i)
#pragma unroll
                for (int j = 0; j < 4; ++j)
                    s[i][j] = __builtin_amdgcn_mfma_f32_16x16x32_bf16(
                        aq[i][kc], bfr[j], s[i][j], 0, 0, 0);
        }

        // ---- online softmax, base-2
        float rmax[2][4];
#pragma unroll
        for (int i = 0; i < 2; ++i)
#pragma unroll
            for (int r = 0; r < 4; ++r)
                rmax[i][r] = fmaxf(fmaxf(s[i][0][r], s[i][1][r]),
                                   fmaxf(s[i][2][r], s[i][3][r]));
#pragma unroll
        for (int d = 1; d < 16; d <<= 1)
#pragma unroll
            for (int i = 0; i < 2; ++i)
#pragma unroll
                for (int r = 0; r < 4; ++r)
                    rmax[i][r] = fmaxf(rmax[i][r], __shfl_xor(rmax[i][r], d, 64));

        int upd = 0;
#pragma unroll
        for (int i = 0; i < 2; ++i)
#pragma unroll
            for (int r = 0; r < 4; ++r) upd |= (rmax[i][r] > mst[i][r]);

        if (__any(upd)) {
#pragma unroll
            for (int i = 0; i < 2; ++i) {
                float alpha[4];
#pragma unroll
                for (int r = 0; r < 4; ++r) {
                    const float mnew = fmaxf(mst[i][r], rmax[i][r]);
                    alpha[r] = EXP2F(mst[i][r] - mnew);
                    mst[i][r] = mnew;
                    lst[i][r] *= alpha[r];
                }
#pragma unroll
                for (int jn = 0; jn < 8; ++jn)
#pragma unroll
                    for (int r = 0; r < 4; ++r) oacc[i][jn][r] *= alpha[r];
            }
        }

        float rsum[2][4];
#pragma unroll
        for (int i = 0; i < 2; ++i)
#pragma unroll
            for (int r = 0; r < 4; ++r) rsum[i][r] = 0.f;
#pragma unroll
        for (int i = 0; i < 2; ++i)
#pragma unroll
            for (int j = 0; j < 4; ++j)
#pragma unroll
                for (int r = 0; r < 4; ++r) {
                    const float p = EXP2F(s[i][j][r] - mst[i][r]);
                    s[i][j][r] = p;
                    rsum[i][r] += p;
                }
#pragma unroll
        for (int d = 1; d < 16; d <<= 1)
#pragma unroll
            for (int i = 0; i < 2; ++i)
#pragma unroll
                for (int r = 0; r < 4; ++r)
                    rsum[i][r] += __shfl_xor(rsum[i][r], d, 64);
#pragma unroll
        for (int i = 0; i < 2; ++i)
#pragma unroll
            for (int r = 0; r < 4; ++r) lst[i][r] += rsum[i][r];

        // ---- write P strip (C-layout -> LDS), packed bf16 convert
        u16* pw = &P_s[w][0];
#pragma unroll
        for (int i = 0; i < 2; ++i)
#pragma unroll
            for (int j = 0; j < 4; ++j) {
                const u32 d0 = pk2(s[i][j][0], s[i][j][1]);
                const u32 d1 = pk2(s[i][j][2], s[i][j][3]);
                const int base = (16 * i + 4 * lq) * 72 + 16 * j + lr;
                pw[base]       = (u16)d0;
                pw[base + 72]  = (u16)(d0 >> 16);
                pw[base + 144] = (u16)d1;
                pw[base + 216] = (u16)(d1 >> 16);
            }

        // ---- O += P V
#pragma unroll
        for (int kc = 0; kc < 2; ++kc) {
            short8 ap[2];
#pragma unroll
            for (int i = 0; i < 2; ++i)
                ap[i] = *(const short8*)(&P_s[w][0] + (16 * i + lr) * 72 + kc * 32 + lq * 8);
#pragma unroll
            for (int jn = 0; jn < 8; ++jn) {
                const int drow = 16 * jn + lr;
                const int cc = (4 * kc + lq) ^ (drow & 7);
                const short8 bv = *(const short8*)(VT_s + drow * 64 + cc * 8);
#pragma unroll
                for (int i = 0; i < 2; ++i)
                    oacc[i][jn] = __builtin_amdgcn_mfma_f32_16x16x32_bf16(
                        ap[i], bv, oacc[i][jn], 0, 0, 0);
            }
        }
        __syncthreads();
    }

    // ---- epilogue: O / l -> bf16
#pragma unroll
    for (int i = 0; i < 2; ++i)
#pragma unroll
        for (int jn = 0; jn < 8; ++jn)
#pragma unroll
            for (int r = 0; r < 4; ++r) {
                const long row = mbase + 16 * i + 4 * lq + r;
                const int d = 16 * jn + lr;
                const float v = oacc[i][jn][r] / lst[i][r];
                Obuf[((long)b * 2048 + row) * 2048 + h * 128 + d] = f2b(v);
            }
}

// ---------------------------------------------------------------- launch
extern "C" void kernel_launch(void* const* d_in, const int* in_sizes, int n_in,
                              void* d_out, int out_size, void* d_ws, size_t ws_size,
                              hipStream_t stream)
{
    (void)in_sizes; (void)n_in; (void)out_size; (void)ws_size;

    u16* p = (u16*)d_ws;
    u16* qbf   = p; p += 8388608;
    u16* kvbf  = p; p += 8388608;
    u16* wqall = p; p += 6291456;   // rows 0..2047 = W_QC, 2048..3071 = W_QR
    u16* wkvall= p; p += 10485760;  // rows 0..2047 = W_KC, 2048..3071 = W_KR, 3072..5119 = W_V
    u16* wob   = p; p += 4194304;
    u16* QCb   = p; p += 8388608;
    u16* QRb   = p; p += 4194304;
    u16* KCb   = p; p += 8388608;
    u16* KRb   = p; p += 4194304;
    u16* VTb   = p; p += 8388608;
    u16* Ob    = p; p += 8388608;

    CastArgs a;
    a.src[0] = (const float*)d_in[0]; a.dst[0] = qbf;               a.scale[0] = QSCALE;
    a.src[1] = (const float*)d_in[1]; a.dst[1] = kvbf;              a.scale[1] = 1.f;
    a.src[2] = (const float*)d_in[2]; a.dst[2] = wqall;             a.scale[2] = 1.f;
    a.src[3] = (const float*)d_in[3]; a.dst[3] = wkvall;            a.scale[3] = 1.f;
    a.src[4] = (const float*)d_in[4]; a.dst[4] = wqall + 4194304;   a.scale[4] = 1.f;
    a.src[5] = (const float*)d_in[5]; a.dst[5] = wkvall + 4194304;  a.scale[5] = 1.f;
    a.src[6] = (const float*)d_in[6]; a.dst[6] = wkvall + 6291456;  a.scale[6] = 1.f;
    a.src[7] = (const float*)d_in[7]; a.dst[7] = wob;               a.scale[7] = 1.f;
    const int blks[8] = {8192, 8192, 4096, 4096, 2048, 2048, 4096, 4096};
    int acc = 0;
    for (int i = 0; i < 8; ++i) { a.startblk[i] = acc; acc += blks[i]; }

    cast_all_k<<<acc, 256, 0, stream>>>(a);

    gemm_bt<0><<<dim3(32, 24), 256, 0, stream>>>(qbf,  wqall,  QCb, QRb, nullptr, 2048);
    gemm_bt<1><<<dim3(32, 40), 256, 0, stream>>>(kvbf, wkvall, KCb, KRb, VTb,     2048);

    flash_attn<<<dim3(16, 16, 2), 256, 0, stream>>>(QCb, QRb, KCb, KRb, VTb, Ob);

    gemm_bt<2><<<dim3(32, 16), 256, 0, stream>>>(Ob, wob, d_out, nullptr, nullptr, 2048);
}

// Round 4
// 472.350 us; speedup vs baseline: 1.2391x; 1.0879x over previous
//
#include <hip/hip_runtime.h>
#include <hip/hip_bf16.h>

typedef unsigned short u16;
typedef unsigned int u32;
typedef unsigned long long u64;
typedef __attribute__((ext_vector_type(8))) short short8;
typedef __attribute__((ext_vector_type(4))) float floatx4;

#if __has_builtin(__builtin_amdgcn_exp2f)
#define EXP2F(x) __builtin_amdgcn_exp2f(x)
#else
#define EXP2F(x) exp2f(x)
#endif

// SCALE * log2(e): softmax runs in base 2, scale pre-folded into Q cast.
#define QSCALE (0.07216878364870323f * 1.4426950408889634f)
#define ROPE_C 0.62286151779f   /* log2(1e6)/32 */

__device__ __forceinline__ u16 f2b(float f) {
    unsigned int x = __builtin_bit_cast(unsigned int, f);
    unsigned int r = (x + 0x7fffu + ((x >> 16) & 1u)) >> 16;   // RNE
    return (u16)r;
}
__device__ __forceinline__ u32 pk2(float a, float b) {
    return (u32)f2b(a) | ((u32)f2b(b) << 16);   // low 16 = a, high 16 = b
}
__device__ __forceinline__ void async16(const void* g, void* l) {
    __builtin_amdgcn_global_load_lds(
        (const __attribute__((address_space(1))) void*)g,
        (__attribute__((address_space(3))) void*)l, 16, 0, 0);
}

// ---------------------------------------------------------------- fused cast
struct CastArgs {
    const float* src[8];
    u16* dst[8];
    float scale[8];
    int startblk[8];
};

__global__ void cast_all_k(CastArgs a)
{
    const int bid = blockIdx.x;
    int s = 0;
#pragma unroll
    for (int i = 1; i < 8; ++i) s += (bid >= a.startblk[i]);
    const long idx = ((long)(bid - a.startblk[s]) * 256 + threadIdx.x) * 4;
    const float4 v = *(const float4*)(a.src[s] + idx);
    const float sc = a.scale[s];
    const u64 pk = (u64)pk2(v.x * sc, v.y * sc)
                 | ((u64)pk2(v.z * sc, v.w * sc) << 32);
    *(u64*)(a.dst[s] + idx) = pk;
}

// ---------------------------------------------------------------- GEMM  C = A(MxK) * B(NxK)^T
// EPI 0 (Q merged, N=3072): col<2048 -> QC bf16 (ld 2048); col>=2048 -> RoPE -> QR (ld 1024)
// EPI 1 (KV merged, N=5120): col<2048 -> KC; 2048..3071 -> RoPE -> KR; >=3072 -> V transposed (b,hd,n)
// EPI 2 (final, N=2048): f32 row-major
template<int EPI>
__global__ void __launch_bounds__(256, 3)
gemm_bt(const u16* __restrict__ A, const u16* __restrict__ Bw,
        void* __restrict__ out0, u16* __restrict__ out1, u16* __restrict__ out2,
        int K)
{
    __shared__ u16 As[128 * 64];
    __shared__ u16 Bs[128 * 64];
    const int t = threadIdx.x;
    const int w = t >> 6;
    const int lane = t & 63;
    const int lq = lane >> 4, lr = lane & 15;
    const long tileM = (long)blockIdx.x * 128;
    const long tileN = (long)blockIdx.y * 128;
    const int wm = (w >> 1) * 64, wn = (w & 1) * 64;

    const floatx4 fzero = {0.f, 0.f, 0.f, 0.f};
    floatx4 acc[4][4];
#pragma unroll
    for (int i = 0; i < 4; ++i)
#pragma unroll
        for (int j = 0; j < 4; ++j) acc[i][j] = fzero;

    for (int k0 = 0; k0 < K; k0 += 64) {
#pragma unroll
        for (int r = 0; r < 4; ++r) {
            const int c = r * 256 + t;
            const int row = c >> 3, cc = c & 7;
            const int gcol = ((cc ^ (row & 7)) << 3);
            async16(A + (tileM + row) * (long)K + k0 + gcol, (char*)As + c * 16);
        }
#pragma unroll
        for (int r = 0; r < 4; ++r) {
            const int c = r * 256 + t;
            const int row = c >> 3, cc = c & 7;
            const int gcol = ((cc ^ (row & 7)) << 3);
            async16(Bw + (tileN + row) * (long)K + k0 + gcol, (char*)Bs + c * 16);
        }
        __builtin_amdgcn_s_waitcnt(0);
        __syncthreads();
#pragma unroll
        for (int kk = 0; kk < 2; ++kk) {
            short8 af[4], bfr[4];
#pragma unroll
            for (int i = 0; i < 4; ++i) {
                const int row = wm + 16 * i + lr;
                const int cc = (kk * 4 + lq) ^ (row & 7);
                af[i] = *(const short8*)(As + row * 64 + cc * 8);
            }
#pragma unroll
            for (int j = 0; j < 4; ++j) {
                const int row = wn + 16 * j + lr;
                const int cc = (kk * 4 + lq) ^ (row & 7);
                bfr[j] = *(const short8*)(Bs + row * 64 + cc * 8);
            }
#pragma unroll
            for (int i = 0; i < 4; ++i)
#pragma unroll
                for (int j = 0; j < 4; ++j)
                    acc[i][j] = __builtin_amdgcn_mfma_f32_16x16x32_bf16(
                        af[i], bfr[j], acc[i][j], 0, 0, 0);
        }
        __syncthreads();
    }

    // ---- epilogue (region is block-uniform: boundaries are multiples of 128)
    const bool isV    = (EPI == 1) && (tileN >= 3072);
    const bool isRope = (EPI != 2) && !isV && (tileN >= 2048);

#pragma unroll
    for (int i = 0; i < 4; ++i) {
#pragma unroll
        for (int j = 0; j < 4; ++j) {
            const long row0 = tileM + wm + 16 * i + 4 * lq;
            const long col  = tileN + wn + 16 * j + lr;
            if (EPI == 2) {
#pragma unroll
                for (int r = 0; r < 4; ++r)
                    ((float*)out0)[(row0 + r) * 2048 + col] = acc[i][j][r];
            } else if (isV) {
                const u32 lo = pk2(acc[i][j][0], acc[i][j][1]);
                const u32 hi = pk2(acc[i][j][2], acc[i][j][3]);
                const long bb = row0 >> 11;
                u16* dst = out2 + ((bb * 2048 + (col - 3072)) << 11) + (row0 & 2047);
                *(uint2*)dst = make_uint2(lo, hi);
            } else if (isRope) {
                const int jj = ((int)col & 63) >> 1;
                const float freq = EXP2F(-ROPE_C * (float)jj);
#pragma unroll
                for (int r = 0; r < 4; ++r) {
                    const float v = acc[i][j][r];
                    const float vp = __shfl_xor(v, 1, 64);
                    const long row = row0 + r;
                    float sn, cs;
                    __sincosf((float)(row & 2047) * freq, &sn, &cs);
                    const float o = (col & 1) ? (v * cs + vp * sn) : (v * cs - vp * sn);
                    out1[row * 1024 + (col - 2048)] = f2b(o);
                }
            } else {
#pragma unroll
                for (int r = 0; r < 4; ++r)
                    ((u16*)out0)[(row0 + r) * 2048 + col] = f2b(acc[i][j][r]);
            }
        }
    }
}

// ---------------------------------------------------------------- flash attention (S^T dataflow)
// grid (M/128, H, B), 256 threads (4 waves), wave owns a 32-row Q strip.
// Q pre-scaled by SCALE*log2e -> softmax in base 2.
// S^T = mfma(K-frag, Q-frag): m lands on lane&15 -> per-lane softmax rows.
// O^T = mfma(V-frag, P-frag): oacc cols = m -> scalar alpha rescale, direct 1/l.
__global__ void __launch_bounds__(256, 2)
flash_attn(const u16* __restrict__ QC, const u16* __restrict__ QR,
           const u16* __restrict__ KC, const u16* __restrict__ KR,
           const u16* __restrict__ VT, u16* __restrict__ Obuf)
{
    __shared__ u16 KC_s[64 * 128];
    __shared__ u16 KR_s[64 * 64];
    __shared__ u16 VT_s[128 * 64];
    __shared__ u16 P_s[4][32 * 72];   // per-wave P strip [m][n], stride 72 (2-way banks: free)

    const int t = threadIdx.x;
    const int w = t >> 6;
    const int lane = t & 63;
    const int lq = lane >> 4, lr = lane & 15;
    const int mbase = blockIdx.x * 128 + w * 32;
    const int h = blockIdx.y, b = blockIdx.z;

    // Q fragments (Y-operand layout [m=lane&15][k=lq*8+j]) in registers
    short8 aq[2][6];
#pragma unroll
    for (int i = 0; i < 2; ++i) {
        const long m = mbase + 16 * i + lr;
        const u16* qc = QC + ((long)b * 2048 + m) * 2048 + h * 128;
        const u16* qr = QR + ((long)b * 2048 + m) * 1024 + h * 64;
#pragma unroll
        for (int kc = 0; kc < 4; ++kc) aq[i][kc]     = *(const short8*)(qc + kc * 32 + lq * 8);
#pragma unroll
        for (int kc = 0; kc < 2; ++kc) aq[i][4 + kc] = *(const short8*)(qr + kc * 32 + lq * 8);
    }

    const floatx4 fzero = {0.f, 0.f, 0.f, 0.f};
    float mst[2], lst[2];
    floatx4 oacc[2][8];   // O^T: rows d (tile jn, 4lq+r), cols m = lr (strip i)
#pragma unroll
    for (int i = 0; i < 2; ++i) {
        mst[i] = -1e30f; lst[i] = 0.f;
#pragma unroll
        for (int jn = 0; jn < 8; ++jn) oacc[i][jn] = fzero;
    }

    const u16* kc_g = KC + ((long)b * 2048) * 2048 + h * 128;
    const u16* kr_g = KR + ((long)b * 2048) * 1024 + h * 64;
    const u16* vt_g = VT + ((long)(b * 16 + h) * 128) * 2048;

    for (int kt = 0; kt < 32; ++kt) {
#pragma unroll
        for (int r = 0; r < 4; ++r) {
            const int c = r * 256 + t;
            const int krow = c >> 4, cc = c & 15;
            const int gc = cc ^ (krow & 7);
            async16(kc_g + (long)(kt * 64 + krow) * 2048 + gc * 8, (char*)KC_s + c * 16);
        }
#pragma unroll
        for (int r = 0; r < 2; ++r) {
            const int c = r * 256 + t;
            const int krow = c >> 3, cc = c & 7;
            const int gc = cc ^ (krow & 7);
            async16(kr_g + (long)(kt * 64 + krow) * 1024 + gc * 8, (char*)KR_s + c * 16);
        }
#pragma unroll
        for (int r = 0; r < 4; ++r) {
            const int c = r * 256 + t;
            const int drow = c >> 3, cc = c & 7;
            const int gc = cc ^ (drow & 7);
            async16(vt_g + (long)drow * 2048 + kt * 64 + gc * 8, (char*)VT_s + c * 16);
        }
        __builtin_amdgcn_s_waitcnt(0);
        __syncthreads();

        // ---- S^T = K Q^T: sT[j][i] rows n (16j+4lq+r), cols m (16i, lane lr)
        floatx4 sT[4][2];
#pragma unroll
        for (int j = 0; j < 4; ++j)
#pragma unroll
            for (int i = 0; i < 2; ++i) sT[j][i] = fzero;
#pragma unroll
        for (int kc = 0; kc < 6; ++kc) {
            short8 kf[4];
#pragma unroll
            for (int j = 0; j < 4; ++j) {
                const int krow = 16 * j + lr;
                if (kc < 4) {
                    const int cc = (4 * kc + lq) ^ (krow & 7);
                    kf[j] = *(const short8*)(KC_s + krow * 128 + cc * 8);
                } else {
                    const int cc = (4 * (kc - 4) + lq) ^ (krow & 7);
                    kf[j] = *(const short8*)(KR_s + krow * 64 + cc * 8);
                }
            }
#pragma unroll
            for (int j = 0; j < 4; ++j)
#pragma unroll
                for (int i = 0; i < 2; ++i)
                    sT[j][i] = __builtin_amdgcn_mfma_f32_16x16x32_bf16(
                        kf[j], aq[i][kc], sT[j][i], 0, 0, 0);
        }

        // ---- online softmax: per-lane over 16 regs, then 2 shuffle rounds (lq groups)
        float rmax[2];
#pragma unroll
        for (int i = 0; i < 2; ++i) {
            float a0 = fmaxf(fmaxf(sT[0][i][0], sT[0][i][1]), fmaxf(sT[0][i][2], sT[0][i][3]));
            float a1 = fmaxf(fmaxf(sT[1][i][0], sT[1][i][1]), fmaxf(sT[1][i][2], sT[1][i][3]));
            float a2 = fmaxf(fmaxf(sT[2][i][0], sT[2][i][1]), fmaxf(sT[2][i][2], sT[2][i][3]));
            float a3 = fmaxf(fmaxf(sT[3][i][0], sT[3][i][1]), fmaxf(sT[3][i][2], sT[3][i][3]));
            rmax[i] = fmaxf(fmaxf(a0, a1), fmaxf(a2, a3));
        }
#pragma unroll
        for (int i = 0; i < 2; ++i) {
            rmax[i] = fmaxf(rmax[i], __shfl_xor(rmax[i], 16, 64));
            rmax[i] = fmaxf(rmax[i], __shfl_xor(rmax[i], 32, 64));
        }

        const int upd = (rmax[0] > mst[0]) | (rmax[1] > mst[1]);
        if (__any(upd)) {
#pragma unroll
            for (int i = 0; i < 2; ++i) {
                const float mnew = fmaxf(mst[i], rmax[i]);
                const float alpha = EXP2F(mst[i] - mnew);
                mst[i] = mnew;
                lst[i] *= alpha;
#pragma unroll
                for (int jn = 0; jn < 8; ++jn)
#pragma unroll
                    for (int r = 0; r < 4; ++r) oacc[i][jn][r] *= alpha;
            }
        }

        float rsum[2] = {0.f, 0.f};
#pragma unroll
        for (int j = 0; j < 4; ++j)
#pragma unroll
            for (int i = 0; i < 2; ++i)
#pragma unroll
                for (int r = 0; r < 4; ++r) {
                    const float p = EXP2F(sT[j][i][r] - mst[i]);
                    sT[j][i][r] = p;
                    rsum[i] += p;
                }
#pragma unroll
        for (int i = 0; i < 2; ++i) {
            rsum[i] += __shfl_xor(rsum[i], 16, 64);
            rsum[i] += __shfl_xor(rsum[i], 32, 64);
            lst[i] += rsum[i];
        }

        // ---- write P strip [m][n]: 4 consecutive n per lane -> b64 writes
        u16* pw = &P_s[w][0];
#pragma unroll
        for (int i = 0; i < 2; ++i)
#pragma unroll
            for (int j = 0; j < 4; ++j) {
                const u32 d0 = pk2(sT[j][i][0], sT[j][i][1]);
                const u32 d1 = pk2(sT[j][i][2], sT[j][i][3]);
                *(uint2*)(pw + (16 * i + lr) * 72 + 16 * j + 4 * lq) = make_uint2(d0, d1);
            }

        // ---- O^T += V^T P^T: mfma(V-frag, P-frag)
#pragma unroll
        for (int kc = 0; kc < 2; ++kc) {
            short8 ap[2];
#pragma unroll
            for (int i = 0; i < 2; ++i)
                ap[i] = *(const short8*)(&P_s[w][0] + (16 * i + lr) * 72 + kc * 32 + lq * 8);
#pragma unroll
            for (int jn = 0; jn < 8; ++jn) {
                const int drow = 16 * jn + lr;
                const int cc = (4 * kc + lq) ^ (drow & 7);
                const short8 bv = *(const short8*)(VT_s + drow * 64 + cc * 8);
#pragma unroll
                for (int i = 0; i < 2; ++i)
                    oacc[i][jn] = __builtin_amdgcn_mfma_f32_16x16x32_bf16(
                        bv, ap[i], oacc[i][jn], 0, 0, 0);
            }
        }
        __syncthreads();
    }

    // ---- epilogue: O^T / l -> bf16, 8B packed stores (4 consecutive d)
#pragma unroll
    for (int i = 0; i < 2; ++i) {
        const float rl = 1.0f / lst[i];
        const long row = (long)b * 2048 + mbase + 16 * i + lr;
#pragma unroll
        for (int jn = 0; jn < 8; ++jn) {
            const u32 lo = pk2(oacc[i][jn][0] * rl, oacc[i][jn][1] * rl);
            const u32 hi = pk2(oacc[i][jn][2] * rl, oacc[i][jn][3] * rl);
            u16* dst = Obuf + row * 2048 + h * 128 + 16 * jn + 4 * lq;
            *(uint2*)dst = make_uint2(lo, hi);
        }
    }
}

// ---------------------------------------------------------------- launch
extern "C" void kernel_launch(void* const* d_in, const int* in_sizes, int n_in,
                              void* d_out, int out_size, void* d_ws, size_t ws_size,
                              hipStream_t stream)
{
    (void)in_sizes; (void)n_in; (void)out_size; (void)ws_size;

    u16* p = (u16*)d_ws;
    u16* qbf   = p; p += 8388608;
    u16* kvbf  = p; p += 8388608;
    u16* wqall = p; p += 6291456;   // rows 0..2047 = W_QC, 2048..3071 = W_QR
    u16* wkvall= p; p += 10485760;  // rows 0..2047 = W_KC, 2048..3071 = W_KR, 3072..5119 = W_V
    u16* wob   = p; p += 4194304;
    u16* QCb   = p; p += 8388608;
    u16* QRb   = p; p += 4194304;
    u16* KCb   = p; p += 8388608;
    u16* KRb   = p; p += 4194304;
    u16* VTb   = p; p += 8388608;
    u16* Ob    = p; p += 8388608;

    CastArgs a;
    a.src[0] = (const float*)d_in[0]; a.dst[0] = qbf;               a.scale[0] = QSCALE;
    a.src[1] = (const float*)d_in[1]; a.dst[1] = kvbf;              a.scale[1] = 1.f;
    a.src[2] = (const float*)d_in[2]; a.dst[2] = wqall;             a.scale[2] = 1.f;
    a.src[3] = (const float*)d_in[3]; a.dst[3] = wkvall;            a.scale[3] = 1.f;
    a.src[4] = (const float*)d_in[4]; a.dst[4] = wqall + 4194304;   a.scale[4] = 1.f;
    a.src[5] = (const float*)d_in[5]; a.dst[5] = wkvall + 4194304;  a.scale[5] = 1.f;
    a.src[6] = (const float*)d_in[6]; a.dst[6] = wkvall + 6291456;  a.scale[6] = 1.f;
    a.src[7] = (const float*)d_in[7]; a.dst[7] = wob;               a.scale[7] = 1.f;
    const int blks[8] = {8192, 8192, 4096, 4096, 2048, 2048, 4096, 4096};
    int acc = 0;
    for (int i = 0; i < 8; ++i) { a.startblk[i] = acc; acc += blks[i]; }

    cast_all_k<<<acc, 256, 0, stream>>>(a);

    gemm_bt<0><<<dim3(32, 24), 256, 0, stream>>>(qbf,  wqall,  QCb, QRb, nullptr, 2048);
    gemm_bt<1><<<dim3(32, 40), 256, 0, stream>>>(kvbf, wkvall, KCb, KRb, VTb,     2048);

    flash_attn<<<dim3(16, 16, 2), 256, 0, stream>>>(QCb, QRb, KCb, KRb, VTb, Ob);

    gemm_bt<2><<<dim3(32, 16), 256, 0, stream>>>(Ob, wob, d_out, nullptr, nullptr, 2048);
}